// Round 11
// baseline (257.563 us; speedup 1.0000x reference)
//
#include <hip/hip_runtime.h>
#include <hip/hip_bf16.h>

#define HID 128
#define RR 50
#define NLAY 3
#define CBSH 9
#define CBSZ 512
#define CPAD (CBSZ * 3)   // max pad slots per coarse bucket
#define ACHUNK 8192

typedef __attribute__((ext_vector_type(8))) short short8;
typedef __attribute__((ext_vector_type(4))) float f32x4;
typedef __attribute__((ext_vector_type(2))) float f32x2;

static __device__ __forceinline__ unsigned short f2bf(float x) {
    unsigned int b = __builtin_bit_cast(unsigned int, x);
    b = b + 0x7FFFu + ((b >> 16) & 1u);
    return (unsigned short)(b >> 16);
}
static __device__ __forceinline__ float bf2f(unsigned int u) {
    return __builtin_bit_cast(float, u << 16);
}
// unpack a packed bf16x2 dword into two f32 (elem0 = low half, elem1 = high half)
static __device__ __forceinline__ f32x2 bfpair(unsigned u) {
    f32x2 r;
    r.x = __builtin_bit_cast(float, u << 16);
    r.y = __builtin_bit_cast(float, u & 0xffff0000u);
    return r;
}
// fast silu: v_rcp instead of IEEE divide
static __device__ __forceinline__ float silu_f(float x) {
    float e = __expf(-x);
    return x * __builtin_amdgcn_rcpf(1.0f + e);
}

// ---------------- geometry: dist (all E) + per-edge {rec, col|-1} + direct bucket counts ----------------
// env = 0.5*(cos(pi*clip(d,0,6)/6)+1) is exactly 0 for d>=6 -> those edges
// contribute silu(x)*0 = 0 to the aggregation. Only d<6 edges survive.
// NO barriers/LDS (round-9 lesson: __syncthreads here = tail-latency serialization).
// Kept-edge bucket counts via FIRE-AND-FORGET global atomics (~40K total, no
// return value -> no wave stall). Also performs the pos->out_pos copy.
__global__ __launch_bounds__(256) void k_geom(
    const int* __restrict__ ei, const int* __restrict__ co,
    const int* __restrict__ eb, const float* __restrict__ cell,
    const float* __restrict__ pos, float* __restrict__ dist_out,
    int2* __restrict__ rec, int* __restrict__ ccol,
    float* __restrict__ out_pos, int* __restrict__ gb, int N3, int E)
{
    int e = blockIdx.x * 256 + threadIdx.x;
    if (e < N3) out_pos[e] = pos[e];
    if (e >= E) return;
    int r = ei[e], c = ei[E + e], b = eb[e];
    float c0 = (float)co[3*e], c1 = (float)co[3*e+1], c2 = (float)co[3*e+2];
    const float* cb = cell + b * 9;
    float v0 = pos[3*r+0] - pos[3*c+0] + c0*cb[0] + c1*cb[3] + c2*cb[6];
    float v1 = pos[3*r+1] - pos[3*c+1] + c0*cb[1] + c1*cb[4] + c2*cb[7];
    float v2 = pos[3*r+2] - pos[3*c+2] + c0*cb[2] + c1*cb[5] + c2*cb[8];
    float d = sqrtf(v0*v0 + v1*v1 + v2*v2);
    dist_out[e] = d;
    bool keep = d < 6.0f;
    ccol[e] = keep ? c : -1;
    if (keep) {
        int di = (int)d;
        di = di < 0 ? 0 : (di > RR - 1 ? RR - 1 : di);
        float envv = 0.5f * (cosf(d * (3.14159265358979323846f / 6.0f)) + 1.0f);
        rec[e] = make_int2((r << 8) | di, __builtin_bit_cast(int, envv));
        atomicAdd(&gb[((unsigned)c) >> CBSH], 1);
    }
}

// ---------------- P1 init by z-gather (layer 0). v/P2 are computed in-kernel by k_layer<FIRST> ----------------
__global__ __launch_bounds__(256) void k_projz(
    const int* __restrict__ z, const unsigned short* __restrict__ P12t,
    unsigned short* __restrict__ P1, int N)
{
    int gid = blockIdx.x * 256 + threadIdx.x;
    if (gid >= N * 16) return;
    int n = gid >> 4, c4 = gid & 15;
    int zz = z[n];
    uint4 t1 = *(const uint4*)(P12t + (size_t)zz * 256 + c4 * 8);
    *(uint4*)(P1 + (size_t)n * HID + c4 * 8) = t1;
}

// ---------------- merged weight prep: pack (640) | Tb (150) | P12t (100) ----------------
__global__ __launch_bounds__(256) void k_wprep(
    const float* __restrict__ We, const float* __restrict__ Wv,
    const float* __restrict__ Wh, const float* __restrict__ dt,
    const float* __restrict__ be, const float* __restrict__ emb,
    unsigned short* __restrict__ WvP, unsigned short* __restrict__ WcP,
    unsigned short* __restrict__ WhP, unsigned short* __restrict__ TbP,
    unsigned short* __restrict__ P12t)
{
    int blk = blockIdx.x;
    if (blk < 640) {
        int t = blk * 256 + threadIdx.x;
        int j = t & 7, l = (t >> 3) & 63, s = (t >> 9) & 3;
        int ln = l & 15, g = l >> 4;
        int k = s * 32 + g * 4 + (j & 3) + ((j >> 2) << 4);
        if (t < 3 * 16384) {
            int i = t >> 14; int nt = (t >> 11) & 7;
            WvP[t] = f2bf(Wv[(size_t)i * 16384 + k * HID + nt * 16 + ln]);
        } else if (t < 3 * 16384 + 3 * 32768) {
            int u = t - 3 * 16384; int i = u >> 15; int nt = (u >> 11) & 15;
            int col = nt * 16 + ln;
            float val = (col < HID) ? We[(size_t)i * 306 * HID + k * HID + col]
                                    : We[(size_t)i * 306 * HID + (HID + k) * HID + (col - HID)];
            WcP[u] = f2bf(val);
        } else {
            int u = t - 3 * 16384 - 3 * 32768; int nt = (u >> 11) & 7;
            WhP[u] = f2bf(Wh[k * HID + nt * 16 + ln]);
        }
    } else if (blk < 640 + NLAY * RR) {
        if (threadIdx.x >= HID) return;
        int row = blk - 640;
        int i = row / RR, r = row % RR;
        int c = threadIdx.x;
        float s = be[i * HID + c];
        const float* w = We + (size_t)i * 306 * HID + 256 * HID + c;
        const float* dr = dt + r * RR;
        for (int k = 0; k < RR; ++k) s += dr[k] * w[k * HID];
        TbP[(i * RR + r) * HID + c] = f2bf(s);
    } else {
        int zz = blk - 640 - NLAY * RR;
        int c = threadIdx.x;
        int cm = c & 127, half = c >> 7;
        const float* er = emb + (size_t)zz * HID;
        const float* w = We + (size_t)(half * 128) * HID + cm;
        float s = 0.f;
        #pragma unroll 8
        for (int k = 0; k < 128; ++k) s += er[k] * w[k * HID];
        P12t[(size_t)zz * 256 + c] = f2bf(s);
    }
}

// ---------------- pass A1: scan coarse counts ----------------
__global__ __launch_bounds__(256) void k_scanA(
    const int* __restrict__ gb, int* __restrict__ gbase,
    int* __restrict__ gcur, int nCB)
{
    __shared__ int ps[256];
    __shared__ int carry;
    int t = threadIdx.x;
    if (t == 0) carry = 0;
    __syncthreads();
    for (int base = 0; base < nCB; base += 256) {
        int v = (base + t < nCB) ? gb[base + t] : 0;
        ps[t] = v; __syncthreads();
        for (int d = 1; d < 256; d <<= 1) {
            int x = (t >= d) ? ps[t - d] : 0;
            __syncthreads();
            ps[t] += x;
            __syncthreads();
        }
        int excl = carry + ps[t] - v;
        if (base + t < nCB) { gbase[base + t] = excl; gcur[base + t] = excl; }
        __syncthreads();
        if (t == 0) carry += ps[255];
        __syncthreads();
    }
    if (t == 0) gbase[nCB] = carry;
}

// ---------------- pass A2: ranked coarse split (skip col<0) ----------------
__global__ __launch_bounds__(256) void k_splitA(
    const int* __restrict__ col, const int2* __restrict__ rec,
    int* __restrict__ gcur, int2* __restrict__ binned,
    int* __restrict__ bcol, int E, int nCB)
{
    __shared__ int lc[1024];
    __shared__ int lres[1024];
    int tid = threadIdx.x;
    for (int i = tid; i < nCB; i += 256) lc[i] = 0;
    __syncthreads();
    int base = blockIdx.x * ACHUNK;
    int end = base + ACHUNK; if (end > E) end = E;
    for (int e = base + tid; e < end; e += 256) {
        int c = col[e];
        if (c >= 0) atomicAdd(&lc[((unsigned)c) >> CBSH], 1);
    }
    __syncthreads();
    for (int i = tid; i < nCB; i += 256) {
        lres[i] = lc[i] ? atomicAdd(&gcur[i], lc[i]) : 0;
        lc[i] = 0;
    }
    __syncthreads();
    for (int e = base + tid; e < end; e += 256) {
        int c = col[e];
        if (c < 0) continue;
        int b = ((unsigned)c) >> CBSH;
        int rank = atomicAdd(&lc[b], 1);
        int p = lres[b] + rank;
        binned[p] = rec[e];
        bcol[p] = c;
    }
}

// ---------------- pass B: per-bucket node sort -> padded meta + noff {off,cnt} ----------------
__global__ __launch_bounds__(256) void k_sortB(
    const int2* __restrict__ binned, const int* __restrict__ bcol,
    const int* __restrict__ gbase, int2* __restrict__ meta,
    int2* __restrict__ noff, int N)
{
    __shared__ int lcnt[CBSZ], lcur[CBSZ], pscan[CBSZ];
    __shared__ int wsum[64];
    const int b = blockIdx.x;
    const int tid = threadIdx.x;
    const int s = gbase[b], e = gbase[b + 1];
    const int mbase = s + b * CPAD;
    for (int i = tid; i < CBSZ; i += 256) { lcnt[i] = 0; lcur[i] = 0; }
    __syncthreads();
    for (int t = s + tid; t < e; t += 256)
        atomicAdd(&lcnt[bcol[t] & (CBSZ - 1)], 1);
    __syncthreads();
    if (tid < 64) {
        int ssum = 0;
        #pragma unroll
        for (int k = 0; k < 8; ++k) {
            int idx = tid * 8 + k;
            int pc = (lcnt[idx] + 3) & ~3;
            pscan[idx] = ssum;
            ssum += pc;
        }
        wsum[tid] = ssum;
    }
    __syncthreads();
    if (tid == 0) {
        int c = 0;
        for (int i = 0; i < 64; ++i) { int t = wsum[i]; wsum[i] = c; c += t; }
    }
    __syncthreads();
    if (tid < 64) {
        #pragma unroll
        for (int k = 0; k < 8; ++k) pscan[tid * 8 + k] += wsum[tid];
    }
    __syncthreads();
    for (int i = tid; i < CBSZ; i += 256) {
        int node = (b << CBSH) + i;
        if (node < N) {
            noff[node] = make_int2(mbase + pscan[i], lcnt[i]);
            int pb = mbase + pscan[i] + lcnt[i];
            int pads = ((lcnt[i] + 3) & ~3) - lcnt[i];
            for (int k = 0; k < pads; ++k) meta[pb + k] = make_int2(0, 0);
        }
    }
    __syncthreads();
    for (int t = s + tid; t < e; t += 256) {
        int local = bcol[t] & (CBSZ - 1);
        int rank = atomicAdd(&lcur[local], 1);
        meta[mbase + pscan[local] + rank] = binned[t];
    }
}

// ---------------- merged layer kernel (512 threads, 8 waves, 32-row tile) ----------------
// P1 is DOUBLE-BUFFERED across layers. P2/v are block-local -> single buffer.
// FIRST (layer 0): v/P2 inputs are pure functions of z -> computed in-kernel
// from emb[z] / P12t[z] (L2-resident tables) instead of global round-trips.
// Phase 0: stage v rows -> SHV (from global v, or emb[z] if FIRST).
// Phase 1: each of 8 waves aggregates 4 nodes -> SH rows (noff/z preloaded
//          lane-parallel; p2 from P2 rows, or P12t[z] if FIRST).
// Phase 2: GEMM1 (each wave owns 16 cols) + residual epilogue -> SH, write v;
//          GEMM2 -> P1out/P2 or f32 head output.
#define PLD(M) (*(const unsigned*)(P1b + (unsigned)((((unsigned)(M).x) & 0xFFFFFF00u) | lane4)))
#define TLDG(M) (*(const unsigned*)(Tb_ + (((((unsigned)(M).x) & 255u) << 8) | lane4)))

#define EP(GG, TBU, MM)                                                       \
    {                                                                         \
        f32x2 xx = bfpair(GG) + (bfpair(TBU) + p2v);                          \
        f32x2 nx = xx * -1.442695041f;                                        \
        f32x2 ee;                                                             \
        ee.x = __builtin_amdgcn_exp2f(nx.x);                                  \
        ee.y = __builtin_amdgcn_exp2f(nx.y);                                  \
        f32x2 dd = ee + 1.0f;                                                 \
        f32x2 rr;                                                             \
        rr.x = __builtin_amdgcn_rcpf(dd.x);                                   \
        rr.y = __builtin_amdgcn_rcpf(dd.y);                                   \
        f32x2 sl = xx * rr;                                                   \
        float evf = __builtin_bit_cast(float, (MM).y);                        \
        av += sl * evf;                                                       \
    }

static __device__ __forceinline__ short8 ldfrag(const unsigned short* A, int r, int s, int g) {
    const char* p = (const char*)(A + r * 136) + s * 64 + g * 8;
    uint2 lo = *(const uint2*)p;
    uint2 hi = *(const uint2*)(p + 32);
    uint4 u; u.x = lo.x; u.y = lo.y; u.z = hi.x; u.w = hi.y;
    return __builtin_bit_cast(short8, u);
}

template<int NT2, bool FINAL, bool FIRST>
__global__ __launch_bounds__(512) void k_layer(
    const unsigned short* __restrict__ P1,    // [N][128] bf16 read buffer (gathered)
    const unsigned short* __restrict__ P2,    // [N][128] bf16 (own-row source; unused if FIRST)
    const unsigned short* __restrict__ TbBf,  // [RR*HID] bf16 (this layer)
    const int2* __restrict__ meta,            // padded sorted {row<<8|di, env}
    const int2* __restrict__ noff,            // {off, cnt} per node
    const int* __restrict__ z,                // [N] (FIRST only)
    const float* __restrict__ emb,            // [MAXZ][128] f32 (FIRST only)
    const unsigned short* __restrict__ P12t,  // [MAXZ][256] bf16 (FIRST only)
    const unsigned short* __restrict__ B1p,   // packed Wv
    const float* __restrict__ b1,             // bv
    unsigned short* __restrict__ v,           // bf16 residual stream
    const unsigned short* __restrict__ B2p,   // packed Wcat/Wh
    const float* __restrict__ b2,             // bh or null
    unsigned short* __restrict__ P1d,         // P1 write buffer (other half)
    unsigned short* __restrict__ P2d,
    float* __restrict__ outd, int N)
{
    __shared__ __align__(16) unsigned short SHB[2 * 32 * 136];  // 17408 B
    unsigned short* SH  = SHB;
    unsigned short* SHV = SHB + 32 * 136;
    const int tid = threadIdx.x;
    const int node0 = blockIdx.x * 32;
    const int w = tid >> 6, l = tid & 63, g = (l >> 4) & 3, ln = l & 15;
    const int lane = l;
    const unsigned lane4 = 4u * (unsigned)lane;

    // phase 0: stage v -> SHV (512 uint4 slots, one pass)
    {
        int r = tid >> 4, c = tid & 15;
        uint4 y4 = make_uint4(0, 0, 0, 0);
        if (node0 + r < N) {
            if (FIRST) {
                int zz = z[node0 + r];
                const float4* ep = (const float4*)(emb + (size_t)zz * HID) + c * 2;
                float4 a = ep[0], b = ep[1];
                y4.x = ((unsigned)f2bf(a.y) << 16) | f2bf(a.x);
                y4.y = ((unsigned)f2bf(a.w) << 16) | f2bf(a.z);
                y4.z = ((unsigned)f2bf(b.y) << 16) | f2bf(b.x);
                y4.w = ((unsigned)f2bf(b.w) << 16) | f2bf(b.z);
            } else {
                y4 = *(const uint4*)(v + (size_t)(node0 + r) * HID + c * 8);
            }
        }
        *(uint4*)(SHV + r * 136 + c * 8) = y4;
    }

    // phase 1: edge aggregation, 4 nodes per wave -> SH rows
    {
        const char* P1b = (const char*)P1;
        const char* Tb_ = (const char*)TbBf;
        const int r0 = w << 2;
        int2 ni = make_int2(0, 0);
        int zq = 0;
        {
            int pn = node0 + r0 + lane;
            if (lane < 4 && pn < N) {
                ni = noff[pn];
                if (FIRST) zq = z[pn];
            }
        }
        #pragma unroll 1
        for (int i = 0; i < 4; ++i) {
            int r = r0 + i;
            unsigned* outp = (unsigned*)(SH + r * 136 + 2 * lane);
            int n = __builtin_amdgcn_readlane(ni.y, i);
            if (n == 0) { *outp = 0u; continue; }
            int s = __builtin_amdgcn_readlane(ni.x, i);
            int node = node0 + r;
            unsigned p2u;
            if (FIRST) {
                int zz = __builtin_amdgcn_readlane(zq, i);
                p2u = *(const unsigned*)(P12t + (size_t)zz * 256 + 128 + 2 * lane);
            } else {
                p2u = *(const unsigned*)(P2 + (size_t)node * HID + 2 * lane);
            }
            n = (n + 3) & ~3;
            f32x2 p2v = bfpair(p2u);
            f32x2 av; av.x = 0.f; av.y = 0.f;
            const int2* mp = meta + s;
            int2 m0 = mp[0], m1 = mp[1], m2 = mp[2], m3 = mp[3];
            unsigned g0 = PLD(m0), g1 = PLD(m1), g2 = PLD(m2), g3 = PLD(m3);
            for (int t = 0; t < n; t += 4) {
                int2 n0 = mp[t + 4], n1 = mp[t + 5], n2 = mp[t + 6], n3 = mp[t + 7];
                unsigned h0 = PLD(n0), h1 = PLD(n1), h2 = PLD(n2), h3 = PLD(n3);
                unsigned t0 = TLDG(m0), t1 = TLDG(m1), t2 = TLDG(m2), t3 = TLDG(m3);
                EP(g0, t0, m0) EP(g1, t1, m1) EP(g2, t2, m2) EP(g3, t3, m3)
                m0 = n0; m1 = n1; m2 = n2; m3 = n3;
                g0 = h0; g1 = h1; g2 = h2; g3 = h3;
            }
            *outp = (((unsigned)f2bf(av.y)) << 16) | (unsigned)f2bf(av.x);
        }
    }

    // phase 2: GEMM1 (16 cols/wave) + residual epilogue + GEMM2
    {
        short8 bf1[4];
        #pragma unroll
        for (int s = 0; s < 4; ++s)
            bf1[s] = *(const short8*)(B1p + ((w * 4 + s) * 64 + l) * 8);
        __syncthreads();                                   // A: SH (agg) + SHV (v) ready
        f32x4 acc[2] = {};
        #pragma unroll
        for (int s = 0; s < 4; ++s)
            #pragma unroll
            for (int mt = 0; mt < 2; ++mt) {
                short8 af = ldfrag(SH, 16 * mt + ln, s, g);
                acc[mt] = __builtin_amdgcn_mfma_f32_16x16x32_bf16(af, bf1[s], acc[mt], 0, 0, 0);
            }
        __syncthreads();                                   // B: all SH reads done
        float bvc = b1[16 * w + ln];
        #pragma unroll
        for (int mt = 0; mt < 2; ++mt) {
            int col = 16 * w + ln;
            #pragma unroll
            for (int j = 0; j < 4; ++j) {
                int r = 16 * mt + 4 * g + j;
                float y = silu_f(acc[mt][j] + bvc);
                float vn = bf2f((unsigned)SHV[r * 136 + col]) + y;
                SH[r * 136 + col] = f2bf(vn);
            }
        }
        __syncthreads();                                   // C: vn complete in SH
        if (!FINAL) {
            int r = tid >> 4, c = tid & 15;
            if (node0 + r < N)
                *(uint4*)(v + (size_t)(node0 + r) * HID + c * 8) =
                    *(const uint4*)(SH + r * 136 + c * 8);
        }
    }

    constexpr int NTW = NT2 / 8;
    short8 bf2[NTW][4];
    #pragma unroll
    for (int nt = 0; nt < NTW; ++nt)
        #pragma unroll
        for (int s = 0; s < 4; ++s)
            bf2[nt][s] = *(const short8*)(B2p + (((w * NTW + nt) * 4 + s) * 64 + l) * 8);
    f32x4 acc2[2][NTW] = {};
    #pragma unroll
    for (int s = 0; s < 4; ++s)
        #pragma unroll
        for (int mt = 0; mt < 2; ++mt) {
            short8 af = ldfrag(SH, 16 * mt + ln, s, g);
            #pragma unroll
            for (int nt = 0; nt < NTW; ++nt)
                acc2[mt][nt] = __builtin_amdgcn_mfma_f32_16x16x32_bf16(af, bf2[nt][s], acc2[mt][nt], 0, 0, 0);
        }
    __syncthreads();                                       // D: SH reads done, buffers free
    if (FINAL) {
        float* fst = (float*)SHB;                          // [32][132] f32 (16896 B)
        int col = w * 16 + ln;                             // NTW == 1
        float bb = b2[col];
        #pragma unroll
        for (int mt = 0; mt < 2; ++mt)
            #pragma unroll
            for (int j = 0; j < 4; ++j) {
                int r = 16 * mt + 4 * g + j;
                fst[r * 132 + col] = acc2[mt][0][j] + bb;
            }
        __syncthreads();                                   // E
        #pragma unroll
        for (int i = 0; i < 2; ++i) {
            int u = tid + 512 * i, r = u >> 5, cg = u & 31;
            if (node0 + r < N)
                *(float4*)(outd + (size_t)(node0 + r) * HID + cg * 4) =
                    *(const float4*)(fst + r * 132 + cg * 4);
        }
    } else {
        #pragma unroll
        for (int nt = 0; nt < NTW; ++nt) {
            int gidx = w * NTW + nt;
            int colm = (gidx * 16 + ln) & 127;
            unsigned short* dst = (gidx < 8) ? SHV : SH;
            #pragma unroll
            for (int mt = 0; mt < 2; ++mt)
                #pragma unroll
                for (int j = 0; j < 4; ++j) {
                    int r = 16 * mt + 4 * g + j;
                    dst[r * 136 + colm] = f2bf(acc2[mt][nt][j]);
                }
        }
        __syncthreads();                                   // E
        {
            int r = tid >> 4, cg = tid & 15;
            if (node0 + r < N) {
                *(uint4*)(P1d + (size_t)(node0 + r) * HID + cg * 8) =
                    *(const uint4*)(SHV + r * 136 + cg * 8);
                *(uint4*)(P2d + (size_t)(node0 + r) * HID + cg * 8) =
                    *(const uint4*)(SH + r * 136 + cg * 8);
            }
        }
    }
}

extern "C" void kernel_launch(void* const* d_in, const int* in_sizes, int n_in,
                              void* d_out, int out_size, void* d_ws, size_t ws_size,
                              hipStream_t stream)
{
    const int*   z    = (const int*)d_in[0];
    const float* pos  = (const float*)d_in[1];
    const float* cell = (const float*)d_in[2];
    const int*   ei   = (const int*)d_in[3];
    const int*   co   = (const int*)d_in[4];
    const int*   eb   = (const int*)d_in[5];
    const float* emb  = (const float*)d_in[6];
    const float* dt   = (const float*)d_in[7];
    const float* We   = (const float*)d_in[8];
    const float* be   = (const float*)d_in[9];
    const float* Wv   = (const float*)d_in[10];
    const float* bv   = (const float*)d_in[11];
    const float* Wh   = (const float*)d_in[12];
    const float* bh   = (const float*)d_in[13];

    const int N = in_sizes[0];
    const int E = in_sizes[5];
    const int MAXZ = in_sizes[6] / HID;
    const int nCB = (N + CBSZ - 1) >> CBSH;
    const size_t metaN = (size_t)E + (size_t)nCB * CPAD + 32;

    char* p = (char*)d_ws;
    unsigned short* v    = (unsigned short*)p;  p += (size_t)N * HID * 2;
    unsigned short* P1a  = (unsigned short*)p;  p += (size_t)N * HID * 2;
    unsigned short* P1b  = (unsigned short*)p;  p += (size_t)N * HID * 2;
    unsigned short* P2   = (unsigned short*)p;  p += (size_t)N * HID * 2;
    int2*  meta  = (int2*)p;                    p += metaN * 8;
    int2*  noff  = (int2*)p;                    p += (size_t)N * 8;
    int*   gb    = (int*)p;                     p += (size_t)(nCB + 1) * 4;
    int*   gbase = (int*)p;                     p += (size_t)(nCB + 1) * 4;
    int*   gcur  = (int*)p;                     p += (size_t)(nCB + 1) * 4;
    unsigned short* TbP = (unsigned short*)p;   p += (size_t)NLAY * RR * HID * 2;
    unsigned short* WvP = (unsigned short*)p;   p += (size_t)3 * 16384 * 2;
    unsigned short* WcP = (unsigned short*)p;   p += (size_t)3 * 32768 * 2;
    unsigned short* WhP = (unsigned short*)p;   p += (size_t)16384 * 2;
    unsigned short* P12t = (unsigned short*)p;  p += (size_t)MAXZ * 256 * 2;

    // transients: rec + binned alias P1a (two E*8 halves); ccol + bcol alias P2.
    // All consumed by k_sortB before k_projz writes P1a.
    int2* rec    = (int2*)P1a;
    int2* binned = (int2*)((char*)P1a + (size_t)E * 8);
    int*  ccol   = (int*)P2;
    int*  bcol   = (int*)((char*)P2 + (size_t)E * 4);

    float* out_v    = (float*)d_out;
    float* out_pos  = out_v + (size_t)N * HID;
    float* out_dist = out_pos + (size_t)N * 3;

    const int nlayer = (N + 31) / 32;
    const int nblkA = (E + ACHUNK - 1) / ACHUNK;
    const int N3 = N * 3;
    int ngeom = (E + 255) / 256;
    if ((N3 + 255) / 256 > ngeom) ngeom = (N3 + 255) / 256;

    hipMemsetAsync(gb, 0, (size_t)(nCB + 1) * 4, stream);
    hipMemsetAsync(meta, 0, metaN * 8, stream);
    k_geom<<<ngeom, 256, 0, stream>>>(ei, co, eb, cell, pos, out_dist, rec, ccol,
                                      out_pos, gb, N3, E);
    k_scanA<<<1, 256, 0, stream>>>(gb, gbase, gcur, nCB);
    k_splitA<<<nblkA, 256, 0, stream>>>(ccol, rec, gcur, binned, bcol, E, nCB);
    k_sortB<<<nCB, 256, 0, stream>>>(binned, bcol, gbase, meta, noff, N);

    k_wprep<<<640 + NLAY * RR + MAXZ, 256, 0, stream>>>(
        We, Wv, Wh, dt, be, emb, WvP, WcP, WhP, TbP, P12t);

    // layer-0 P1 via z-gather (after sortB: rec/ccol/binned/bcol dead)
    k_projz<<<(N * 16 + 255) / 256, 256, 0, stream>>>(z, P12t, P1a, N);

    k_layer<16, false, true><<<nlayer, 512, 0, stream>>>(
        P1a, nullptr, TbP, meta, noff, z, emb, P12t,
        WvP, bv, v, WcP + (size_t)32768, nullptr, P1b, P2, nullptr, N);
    k_layer<16, false, false><<<nlayer, 512, 0, stream>>>(
        P1b, P2, TbP + (size_t)RR * HID, meta, noff, nullptr, nullptr, nullptr,
        WvP + (size_t)16384, bv + (size_t)HID, v,
        WcP + (size_t)2 * 32768, nullptr, P1a, P2, nullptr, N);
    k_layer<8, true, false><<<nlayer, 512, 0, stream>>>(
        P1a, P2, TbP + (size_t)2 * RR * HID, meta, noff, nullptr, nullptr, nullptr,
        WvP + (size_t)2 * 16384, bv + (size_t)2 * HID, v,
        WhP, bh, nullptr, nullptr, out_v, N);
}

// Round 12
// 201.250 us; speedup vs baseline: 1.2798x; 1.2798x over previous
//
#include <hip/hip_runtime.h>
#include <hip/hip_bf16.h>

#define HID 128
#define RR 50
#define NLAY 3
#define CBSH 9
#define CBSZ 512
#define CPAD (CBSZ * 3)   // max pad slots per coarse bucket
#define ACHUNK 8192

typedef __attribute__((ext_vector_type(8))) short short8;
typedef __attribute__((ext_vector_type(4))) float f32x4;
typedef __attribute__((ext_vector_type(2))) float f32x2;

static __device__ __forceinline__ unsigned short f2bf(float x) {
    unsigned int b = __builtin_bit_cast(unsigned int, x);
    b = b + 0x7FFFu + ((b >> 16) & 1u);
    return (unsigned short)(b >> 16);
}
static __device__ __forceinline__ float bf2f(unsigned int u) {
    return __builtin_bit_cast(float, u << 16);
}
// unpack a packed bf16x2 dword into two f32 (elem0 = low half, elem1 = high half)
static __device__ __forceinline__ f32x2 bfpair(unsigned u) {
    f32x2 r;
    r.x = __builtin_bit_cast(float, u << 16);
    r.y = __builtin_bit_cast(float, u & 0xffff0000u);
    return r;
}
// fast silu: v_rcp instead of IEEE divide
static __device__ __forceinline__ float silu_f(float x) {
    float e = __expf(-x);
    return x * __builtin_amdgcn_rcpf(1.0f + e);
}

// ---------------- geometry: dist (all E) + per-edge {rec, col|-1} filter flags ----------------
// env = 0.5*(cos(pi*clip(d,0,6)/6)+1) is exactly 0 for d>=6 -> those edges
// contribute silu(x)*0 = 0 to the aggregation. Only d<6 edges survive.
// PURE STREAMING: no barriers/LDS (round-9: __syncthreads = tail-latency
// serialization, 27->70us) and no global atomics (round-11: 196-counter
// contention across 8 XCD L2s = 27->86us). Counting lives in k_cntA.
// Also performs the pos->out_pos copy (folded k_copy).
__global__ __launch_bounds__(256) void k_geom(
    const int* __restrict__ ei, const int* __restrict__ co,
    const int* __restrict__ eb, const float* __restrict__ cell,
    const float* __restrict__ pos, float* __restrict__ dist_out,
    int2* __restrict__ rec, int* __restrict__ ccol,
    float* __restrict__ out_pos, int N3, int E)
{
    int e = blockIdx.x * 256 + threadIdx.x;
    if (e < N3) out_pos[e] = pos[e];
    if (e >= E) return;
    int r = ei[e], c = ei[E + e], b = eb[e];
    float c0 = (float)co[3*e], c1 = (float)co[3*e+1], c2 = (float)co[3*e+2];
    const float* cb = cell + b * 9;
    float v0 = pos[3*r+0] - pos[3*c+0] + c0*cb[0] + c1*cb[3] + c2*cb[6];
    float v1 = pos[3*r+1] - pos[3*c+1] + c0*cb[1] + c1*cb[4] + c2*cb[7];
    float v2 = pos[3*r+2] - pos[3*c+2] + c0*cb[2] + c1*cb[5] + c2*cb[8];
    float d = sqrtf(v0*v0 + v1*v1 + v2*v2);
    dist_out[e] = d;
    bool keep = d < 6.0f;
    ccol[e] = keep ? c : -1;
    if (keep) {
        int di = (int)d;
        di = di < 0 ? 0 : (di > RR - 1 ? RR - 1 : di);
        float envv = 0.5f * (cosf(d * (3.14159265358979323846f / 6.0f)) + 1.0f);
        rec[e] = make_int2((r << 8) | di, __builtin_bit_cast(int, envv));
    }
}

// ---------------- pass A0: coarse-bucket counts (LDS-aggregated, skip col<0) ----------------
__global__ __launch_bounds__(256) void k_cntA(
    const int* __restrict__ col, int* __restrict__ gb, int E, int nCB)
{
    __shared__ int lc[1024];
    int tid = threadIdx.x;
    for (int i = tid; i < nCB; i += 256) lc[i] = 0;
    __syncthreads();
    int base = blockIdx.x * ACHUNK;
    int end = base + ACHUNK; if (end > E) end = E;
    for (int e = base + tid; e < end; e += 256) {
        int c = col[e];
        if (c >= 0) atomicAdd(&lc[((unsigned)c) >> CBSH], 1);
    }
    __syncthreads();
    for (int i = tid; i < nCB; i += 256)
        if (lc[i]) atomicAdd(&gb[i], lc[i]);
}

// ---------------- P1 init by z-gather (layer 0). v/P2 are computed in-kernel by k_layer<FIRST> ----------------
__global__ __launch_bounds__(256) void k_projz(
    const int* __restrict__ z, const unsigned short* __restrict__ P12t,
    unsigned short* __restrict__ P1, int N)
{
    int gid = blockIdx.x * 256 + threadIdx.x;
    if (gid >= N * 16) return;
    int n = gid >> 4, c4 = gid & 15;
    int zz = z[n];
    uint4 t1 = *(const uint4*)(P12t + (size_t)zz * 256 + c4 * 8);
    *(uint4*)(P1 + (size_t)n * HID + c4 * 8) = t1;
}

// ---------------- merged weight prep: pack (640) | Tb (150) | P12t (100) ----------------
__global__ __launch_bounds__(256) void k_wprep(
    const float* __restrict__ We, const float* __restrict__ Wv,
    const float* __restrict__ Wh, const float* __restrict__ dt,
    const float* __restrict__ be, const float* __restrict__ emb,
    unsigned short* __restrict__ WvP, unsigned short* __restrict__ WcP,
    unsigned short* __restrict__ WhP, unsigned short* __restrict__ TbP,
    unsigned short* __restrict__ P12t)
{
    int blk = blockIdx.x;
    if (blk < 640) {
        int t = blk * 256 + threadIdx.x;
        int j = t & 7, l = (t >> 3) & 63, s = (t >> 9) & 3;
        int ln = l & 15, g = l >> 4;
        int k = s * 32 + g * 4 + (j & 3) + ((j >> 2) << 4);
        if (t < 3 * 16384) {
            int i = t >> 14; int nt = (t >> 11) & 7;
            WvP[t] = f2bf(Wv[(size_t)i * 16384 + k * HID + nt * 16 + ln]);
        } else if (t < 3 * 16384 + 3 * 32768) {
            int u = t - 3 * 16384; int i = u >> 15; int nt = (u >> 11) & 15;
            int col = nt * 16 + ln;
            float val = (col < HID) ? We[(size_t)i * 306 * HID + k * HID + col]
                                    : We[(size_t)i * 306 * HID + (HID + k) * HID + (col - HID)];
            WcP[u] = f2bf(val);
        } else {
            int u = t - 3 * 16384 - 3 * 32768; int nt = (u >> 11) & 7;
            WhP[u] = f2bf(Wh[k * HID + nt * 16 + ln]);
        }
    } else if (blk < 640 + NLAY * RR) {
        if (threadIdx.x >= HID) return;
        int row = blk - 640;
        int i = row / RR, r = row % RR;
        int c = threadIdx.x;
        float s = be[i * HID + c];
        const float* w = We + (size_t)i * 306 * HID + 256 * HID + c;
        const float* dr = dt + r * RR;
        for (int k = 0; k < RR; ++k) s += dr[k] * w[k * HID];
        TbP[(i * RR + r) * HID + c] = f2bf(s);
    } else {
        int zz = blk - 640 - NLAY * RR;
        int c = threadIdx.x;
        int cm = c & 127, half = c >> 7;
        const float* er = emb + (size_t)zz * HID;
        const float* w = We + (size_t)(half * 128) * HID + cm;
        float s = 0.f;
        #pragma unroll 8
        for (int k = 0; k < 128; ++k) s += er[k] * w[k * HID];
        P12t[(size_t)zz * 256 + c] = f2bf(s);
    }
}

// ---------------- pass A1: scan coarse counts ----------------
__global__ __launch_bounds__(256) void k_scanA(
    const int* __restrict__ gb, int* __restrict__ gbase,
    int* __restrict__ gcur, int nCB)
{
    __shared__ int ps[256];
    __shared__ int carry;
    int t = threadIdx.x;
    if (t == 0) carry = 0;
    __syncthreads();
    for (int base = 0; base < nCB; base += 256) {
        int v = (base + t < nCB) ? gb[base + t] : 0;
        ps[t] = v; __syncthreads();
        for (int d = 1; d < 256; d <<= 1) {
            int x = (t >= d) ? ps[t - d] : 0;
            __syncthreads();
            ps[t] += x;
            __syncthreads();
        }
        int excl = carry + ps[t] - v;
        if (base + t < nCB) { gbase[base + t] = excl; gcur[base + t] = excl; }
        __syncthreads();
        if (t == 0) carry += ps[255];
        __syncthreads();
    }
    if (t == 0) gbase[nCB] = carry;
}

// ---------------- pass A2: ranked coarse split (skip col<0) ----------------
__global__ __launch_bounds__(256) void k_splitA(
    const int* __restrict__ col, const int2* __restrict__ rec,
    int* __restrict__ gcur, int2* __restrict__ binned,
    int* __restrict__ bcol, int E, int nCB)
{
    __shared__ int lc[1024];
    __shared__ int lres[1024];
    int tid = threadIdx.x;
    for (int i = tid; i < nCB; i += 256) lc[i] = 0;
    __syncthreads();
    int base = blockIdx.x * ACHUNK;
    int end = base + ACHUNK; if (end > E) end = E;
    for (int e = base + tid; e < end; e += 256) {
        int c = col[e];
        if (c >= 0) atomicAdd(&lc[((unsigned)c) >> CBSH], 1);
    }
    __syncthreads();
    for (int i = tid; i < nCB; i += 256) {
        lres[i] = lc[i] ? atomicAdd(&gcur[i], lc[i]) : 0;
        lc[i] = 0;
    }
    __syncthreads();
    for (int e = base + tid; e < end; e += 256) {
        int c = col[e];
        if (c < 0) continue;
        int b = ((unsigned)c) >> CBSH;
        int rank = atomicAdd(&lc[b], 1);
        int p = lres[b] + rank;
        binned[p] = rec[e];
        bcol[p] = c;
    }
}

// ---------------- pass B: per-bucket node sort -> padded meta + noff {off,cnt} ----------------
__global__ __launch_bounds__(256) void k_sortB(
    const int2* __restrict__ binned, const int* __restrict__ bcol,
    const int* __restrict__ gbase, int2* __restrict__ meta,
    int2* __restrict__ noff, int N)
{
    __shared__ int lcnt[CBSZ], lcur[CBSZ], pscan[CBSZ];
    __shared__ int wsum[64];
    const int b = blockIdx.x;
    const int tid = threadIdx.x;
    const int s = gbase[b], e = gbase[b + 1];
    const int mbase = s + b * CPAD;
    for (int i = tid; i < CBSZ; i += 256) { lcnt[i] = 0; lcur[i] = 0; }
    __syncthreads();
    for (int t = s + tid; t < e; t += 256)
        atomicAdd(&lcnt[bcol[t] & (CBSZ - 1)], 1);
    __syncthreads();
    if (tid < 64) {
        int ssum = 0;
        #pragma unroll
        for (int k = 0; k < 8; ++k) {
            int idx = tid * 8 + k;
            int pc = (lcnt[idx] + 3) & ~3;
            pscan[idx] = ssum;
            ssum += pc;
        }
        wsum[tid] = ssum;
    }
    __syncthreads();
    if (tid == 0) {
        int c = 0;
        for (int i = 0; i < 64; ++i) { int t = wsum[i]; wsum[i] = c; c += t; }
    }
    __syncthreads();
    if (tid < 64) {
        #pragma unroll
        for (int k = 0; k < 8; ++k) pscan[tid * 8 + k] += wsum[tid];
    }
    __syncthreads();
    for (int i = tid; i < CBSZ; i += 256) {
        int node = (b << CBSH) + i;
        if (node < N) {
            noff[node] = make_int2(mbase + pscan[i], lcnt[i]);
            int pb = mbase + pscan[i] + lcnt[i];
            int pads = ((lcnt[i] + 3) & ~3) - lcnt[i];
            for (int k = 0; k < pads; ++k) meta[pb + k] = make_int2(0, 0);
        }
    }
    __syncthreads();
    for (int t = s + tid; t < e; t += 256) {
        int local = bcol[t] & (CBSZ - 1);
        int rank = atomicAdd(&lcur[local], 1);
        meta[mbase + pscan[local] + rank] = binned[t];
    }
}

// ---------------- merged layer kernel (512 threads, 8 waves, 32-row tile) ----------------
// P1 is DOUBLE-BUFFERED across layers. P2/v are block-local -> single buffer.
// FIRST (layer 0): v/P2 inputs are pure functions of z -> computed in-kernel
// from emb[z] / P12t[z] (L2-resident tables) instead of global round-trips.
// Phase 0: stage v rows -> SHV (from global v, or emb[z] if FIRST).
// Phase 1: each of 8 waves aggregates 4 nodes -> SH rows (noff/z preloaded
//          lane-parallel; p2 from P2 rows, or P12t[z] if FIRST).
// Phase 2: GEMM1 (each wave owns 16 cols) + residual epilogue -> SH, write v;
//          GEMM2 -> P1out/P2 or f32 head output.
#define PLD(M) (*(const unsigned*)(P1b + (unsigned)((((unsigned)(M).x) & 0xFFFFFF00u) | lane4)))
#define TLDG(M) (*(const unsigned*)(Tb_ + (((((unsigned)(M).x) & 255u) << 8) | lane4)))

#define EP(GG, TBU, MM)                                                       \
    {                                                                         \
        f32x2 xx = bfpair(GG) + (bfpair(TBU) + p2v);                          \
        f32x2 nx = xx * -1.442695041f;                                        \
        f32x2 ee;                                                             \
        ee.x = __builtin_amdgcn_exp2f(nx.x);                                  \
        ee.y = __builtin_amdgcn_exp2f(nx.y);                                  \
        f32x2 dd = ee + 1.0f;                                                 \
        f32x2 rr;                                                             \
        rr.x = __builtin_amdgcn_rcpf(dd.x);                                   \
        rr.y = __builtin_amdgcn_rcpf(dd.y);                                   \
        f32x2 sl = xx * rr;                                                   \
        float evf = __builtin_bit_cast(float, (MM).y);                        \
        av += sl * evf;                                                       \
    }

static __device__ __forceinline__ short8 ldfrag(const unsigned short* A, int r, int s, int g) {
    const char* p = (const char*)(A + r * 136) + s * 64 + g * 8;
    uint2 lo = *(const uint2*)p;
    uint2 hi = *(const uint2*)(p + 32);
    uint4 u; u.x = lo.x; u.y = lo.y; u.z = hi.x; u.w = hi.y;
    return __builtin_bit_cast(short8, u);
}

template<int NT2, bool FINAL, bool FIRST>
__global__ __launch_bounds__(512) void k_layer(
    const unsigned short* __restrict__ P1,    // [N][128] bf16 read buffer (gathered)
    const unsigned short* __restrict__ P2,    // [N][128] bf16 (own-row source; unused if FIRST)
    const unsigned short* __restrict__ TbBf,  // [RR*HID] bf16 (this layer)
    const int2* __restrict__ meta,            // padded sorted {row<<8|di, env}
    const int2* __restrict__ noff,            // {off, cnt} per node
    const int* __restrict__ z,                // [N] (FIRST only)
    const float* __restrict__ emb,            // [MAXZ][128] f32 (FIRST only)
    const unsigned short* __restrict__ P12t,  // [MAXZ][256] bf16 (FIRST only)
    const unsigned short* __restrict__ B1p,   // packed Wv
    const float* __restrict__ b1,             // bv
    unsigned short* __restrict__ v,           // bf16 residual stream
    const unsigned short* __restrict__ B2p,   // packed Wcat/Wh
    const float* __restrict__ b2,             // bh or null
    unsigned short* __restrict__ P1d,         // P1 write buffer (other half)
    unsigned short* __restrict__ P2d,
    float* __restrict__ outd, int N)
{
    __shared__ __align__(16) unsigned short SHB[2 * 32 * 136];  // 17408 B
    unsigned short* SH  = SHB;
    unsigned short* SHV = SHB + 32 * 136;
    const int tid = threadIdx.x;
    const int node0 = blockIdx.x * 32;
    const int w = tid >> 6, l = tid & 63, g = (l >> 4) & 3, ln = l & 15;
    const int lane = l;
    const unsigned lane4 = 4u * (unsigned)lane;

    // phase 0: stage v -> SHV (512 uint4 slots, one pass)
    {
        int r = tid >> 4, c = tid & 15;
        uint4 y4 = make_uint4(0, 0, 0, 0);
        if (node0 + r < N) {
            if (FIRST) {
                int zz = z[node0 + r];
                const float4* ep = (const float4*)(emb + (size_t)zz * HID) + c * 2;
                float4 a = ep[0], b = ep[1];
                y4.x = ((unsigned)f2bf(a.y) << 16) | f2bf(a.x);
                y4.y = ((unsigned)f2bf(a.w) << 16) | f2bf(a.z);
                y4.z = ((unsigned)f2bf(b.y) << 16) | f2bf(b.x);
                y4.w = ((unsigned)f2bf(b.w) << 16) | f2bf(b.z);
            } else {
                y4 = *(const uint4*)(v + (size_t)(node0 + r) * HID + c * 8);
            }
        }
        *(uint4*)(SHV + r * 136 + c * 8) = y4;
    }

    // phase 1: edge aggregation, 4 nodes per wave -> SH rows
    {
        const char* P1b = (const char*)P1;
        const char* Tb_ = (const char*)TbBf;
        const int r0 = w << 2;
        int2 ni = make_int2(0, 0);
        int zq = 0;
        {
            int pn = node0 + r0 + lane;
            if (lane < 4 && pn < N) {
                ni = noff[pn];
                if (FIRST) zq = z[pn];
            }
        }
        #pragma unroll 1
        for (int i = 0; i < 4; ++i) {
            int r = r0 + i;
            unsigned* outp = (unsigned*)(SH + r * 136 + 2 * lane);
            int n = __builtin_amdgcn_readlane(ni.y, i);
            if (n == 0) { *outp = 0u; continue; }
            int s = __builtin_amdgcn_readlane(ni.x, i);
            int node = node0 + r;
            unsigned p2u;
            if (FIRST) {
                int zz = __builtin_amdgcn_readlane(zq, i);
                p2u = *(const unsigned*)(P12t + (size_t)zz * 256 + 128 + 2 * lane);
            } else {
                p2u = *(const unsigned*)(P2 + (size_t)node * HID + 2 * lane);
            }
            n = (n + 3) & ~3;
            f32x2 p2v = bfpair(p2u);
            f32x2 av; av.x = 0.f; av.y = 0.f;
            const int2* mp = meta + s;
            int2 m0 = mp[0], m1 = mp[1], m2 = mp[2], m3 = mp[3];
            unsigned g0 = PLD(m0), g1 = PLD(m1), g2 = PLD(m2), g3 = PLD(m3);
            for (int t = 0; t < n; t += 4) {
                int2 n0 = mp[t + 4], n1 = mp[t + 5], n2 = mp[t + 6], n3 = mp[t + 7];
                unsigned h0 = PLD(n0), h1 = PLD(n1), h2 = PLD(n2), h3 = PLD(n3);
                unsigned t0 = TLDG(m0), t1 = TLDG(m1), t2 = TLDG(m2), t3 = TLDG(m3);
                EP(g0, t0, m0) EP(g1, t1, m1) EP(g2, t2, m2) EP(g3, t3, m3)
                m0 = n0; m1 = n1; m2 = n2; m3 = n3;
                g0 = h0; g1 = h1; g2 = h2; g3 = h3;
            }
            *outp = (((unsigned)f2bf(av.y)) << 16) | (unsigned)f2bf(av.x);
        }
    }

    // phase 2: GEMM1 (16 cols/wave) + residual epilogue + GEMM2
    {
        short8 bf1[4];
        #pragma unroll
        for (int s = 0; s < 4; ++s)
            bf1[s] = *(const short8*)(B1p + ((w * 4 + s) * 64 + l) * 8);
        __syncthreads();                                   // A: SH (agg) + SHV (v) ready
        f32x4 acc[2] = {};
        #pragma unroll
        for (int s = 0; s < 4; ++s)
            #pragma unroll
            for (int mt = 0; mt < 2; ++mt) {
                short8 af = ldfrag(SH, 16 * mt + ln, s, g);
                acc[mt] = __builtin_amdgcn_mfma_f32_16x16x32_bf16(af, bf1[s], acc[mt], 0, 0, 0);
            }
        __syncthreads();                                   // B: all SH reads done
        float bvc = b1[16 * w + ln];
        #pragma unroll
        for (int mt = 0; mt < 2; ++mt) {
            int col = 16 * w + ln;
            #pragma unroll
            for (int j = 0; j < 4; ++j) {
                int r = 16 * mt + 4 * g + j;
                float y = silu_f(acc[mt][j] + bvc);
                float vn = bf2f((unsigned)SHV[r * 136 + col]) + y;
                SH[r * 136 + col] = f2bf(vn);
            }
        }
        __syncthreads();                                   // C: vn complete in SH
        if (!FINAL) {
            int r = tid >> 4, c = tid & 15;
            if (node0 + r < N)
                *(uint4*)(v + (size_t)(node0 + r) * HID + c * 8) =
                    *(const uint4*)(SH + r * 136 + c * 8);
        }
    }

    constexpr int NTW = NT2 / 8;
    short8 bf2[NTW][4];
    #pragma unroll
    for (int nt = 0; nt < NTW; ++nt)
        #pragma unroll
        for (int s = 0; s < 4; ++s)
            bf2[nt][s] = *(const short8*)(B2p + (((w * NTW + nt) * 4 + s) * 64 + l) * 8);
    f32x4 acc2[2][NTW] = {};
    #pragma unroll
    for (int s = 0; s < 4; ++s)
        #pragma unroll
        for (int mt = 0; mt < 2; ++mt) {
            short8 af = ldfrag(SH, 16 * mt + ln, s, g);
            #pragma unroll
            for (int nt = 0; nt < NTW; ++nt)
                acc2[mt][nt] = __builtin_amdgcn_mfma_f32_16x16x32_bf16(af, bf2[nt][s], acc2[mt][nt], 0, 0, 0);
        }
    __syncthreads();                                       // D: SH reads done, buffers free
    if (FINAL) {
        float* fst = (float*)SHB;                          // [32][132] f32 (16896 B)
        int col = w * 16 + ln;                             // NTW == 1
        float bb = b2[col];
        #pragma unroll
        for (int mt = 0; mt < 2; ++mt)
            #pragma unroll
            for (int j = 0; j < 4; ++j) {
                int r = 16 * mt + 4 * g + j;
                fst[r * 132 + col] = acc2[mt][0][j] + bb;
            }
        __syncthreads();                                   // E
        #pragma unroll
        for (int i = 0; i < 2; ++i) {
            int u = tid + 512 * i, r = u >> 5, cg = u & 31;
            if (node0 + r < N)
                *(float4*)(outd + (size_t)(node0 + r) * HID + cg * 4) =
                    *(const float4*)(fst + r * 132 + cg * 4);
        }
    } else {
        #pragma unroll
        for (int nt = 0; nt < NTW; ++nt) {
            int gidx = w * NTW + nt;
            int colm = (gidx * 16 + ln) & 127;
            unsigned short* dst = (gidx < 8) ? SHV : SH;
            #pragma unroll
            for (int mt = 0; mt < 2; ++mt)
                #pragma unroll
                for (int j = 0; j < 4; ++j) {
                    int r = 16 * mt + 4 * g + j;
                    dst[r * 136 + colm] = f2bf(acc2[mt][nt][j]);
                }
        }
        __syncthreads();                                   // E
        {
            int r = tid >> 4, cg = tid & 15;
            if (node0 + r < N) {
                *(uint4*)(P1d + (size_t)(node0 + r) * HID + cg * 8) =
                    *(const uint4*)(SHV + r * 136 + cg * 8);
                *(uint4*)(P2d + (size_t)(node0 + r) * HID + cg * 8) =
                    *(const uint4*)(SH + r * 136 + cg * 8);
            }
        }
    }
}

extern "C" void kernel_launch(void* const* d_in, const int* in_sizes, int n_in,
                              void* d_out, int out_size, void* d_ws, size_t ws_size,
                              hipStream_t stream)
{
    const int*   z    = (const int*)d_in[0];
    const float* pos  = (const float*)d_in[1];
    const float* cell = (const float*)d_in[2];
    const int*   ei   = (const int*)d_in[3];
    const int*   co   = (const int*)d_in[4];
    const int*   eb   = (const int*)d_in[5];
    const float* emb  = (const float*)d_in[6];
    const float* dt   = (const float*)d_in[7];
    const float* We   = (const float*)d_in[8];
    const float* be   = (const float*)d_in[9];
    const float* Wv   = (const float*)d_in[10];
    const float* bv   = (const float*)d_in[11];
    const float* Wh   = (const float*)d_in[12];
    const float* bh   = (const float*)d_in[13];

    const int N = in_sizes[0];
    const int E = in_sizes[5];
    const int MAXZ = in_sizes[6] / HID;
    const int nCB = (N + CBSZ - 1) >> CBSH;
    const size_t metaN = (size_t)E + (size_t)nCB * CPAD + 32;

    char* p = (char*)d_ws;
    unsigned short* v    = (unsigned short*)p;  p += (size_t)N * HID * 2;
    unsigned short* P1a  = (unsigned short*)p;  p += (size_t)N * HID * 2;
    unsigned short* P1b  = (unsigned short*)p;  p += (size_t)N * HID * 2;
    unsigned short* P2   = (unsigned short*)p;  p += (size_t)N * HID * 2;
    int2*  meta  = (int2*)p;                    p += metaN * 8;
    int2*  noff  = (int2*)p;                    p += (size_t)N * 8;
    int*   gb    = (int*)p;                     p += (size_t)(nCB + 1) * 4;
    int*   gbase = (int*)p;                     p += (size_t)(nCB + 1) * 4;
    int*   gcur  = (int*)p;                     p += (size_t)(nCB + 1) * 4;
    unsigned short* TbP = (unsigned short*)p;   p += (size_t)NLAY * RR * HID * 2;
    unsigned short* WvP = (unsigned short*)p;   p += (size_t)3 * 16384 * 2;
    unsigned short* WcP = (unsigned short*)p;   p += (size_t)3 * 32768 * 2;
    unsigned short* WhP = (unsigned short*)p;   p += (size_t)16384 * 2;
    unsigned short* P12t = (unsigned short*)p;  p += (size_t)MAXZ * 256 * 2;

    // transients: rec + binned alias P1a (two E*8 halves); ccol + bcol alias P2.
    // All consumed by k_sortB before k_projz writes P1a.
    int2* rec    = (int2*)P1a;
    int2* binned = (int2*)((char*)P1a + (size_t)E * 8);
    int*  ccol   = (int*)P2;
    int*  bcol   = (int*)((char*)P2 + (size_t)E * 4);

    float* out_v    = (float*)d_out;
    float* out_pos  = out_v + (size_t)N * HID;
    float* out_dist = out_pos + (size_t)N * 3;

    const int nlayer = (N + 31) / 32;
    const int nblkA = (E + ACHUNK - 1) / ACHUNK;
    const int N3 = N * 3;
    int ngeom = (E + 255) / 256;
    if ((N3 + 255) / 256 > ngeom) ngeom = (N3 + 255) / 256;

    hipMemsetAsync(gb, 0, (size_t)(nCB + 1) * 4, stream);
    hipMemsetAsync(meta, 0, metaN * 8, stream);
    k_geom<<<ngeom, 256, 0, stream>>>(ei, co, eb, cell, pos, out_dist, rec, ccol,
                                      out_pos, N3, E);
    k_cntA<<<nblkA, 256, 0, stream>>>(ccol, gb, E, nCB);
    k_scanA<<<1, 256, 0, stream>>>(gb, gbase, gcur, nCB);
    k_splitA<<<nblkA, 256, 0, stream>>>(ccol, rec, gcur, binned, bcol, E, nCB);
    k_sortB<<<nCB, 256, 0, stream>>>(binned, bcol, gbase, meta, noff, N);

    k_wprep<<<640 + NLAY * RR + MAXZ, 256, 0, stream>>>(
        We, Wv, Wh, dt, be, emb, WvP, WcP, WhP, TbP, P12t);

    // layer-0 P1 via z-gather (after sortB: rec/ccol/binned/bcol dead)
    k_projz<<<(N * 16 + 255) / 256, 256, 0, stream>>>(z, P12t, P1a, N);

    k_layer<16, false, true><<<nlayer, 512, 0, stream>>>(
        P1a, nullptr, TbP, meta, noff, z, emb, P12t,
        WvP, bv, v, WcP + (size_t)32768, nullptr, P1b, P2, nullptr, N);
    k_layer<16, false, false><<<nlayer, 512, 0, stream>>>(
        P1b, P2, TbP + (size_t)RR * HID, meta, noff, nullptr, nullptr, nullptr,
        WvP + (size_t)16384, bv + (size_t)HID, v,
        WcP + (size_t)2 * 32768, nullptr, P1a, P2, nullptr, N);
    k_layer<8, true, false><<<nlayer, 512, 0, stream>>>(
        P1a, P2, TbP + (size_t)2 * RR * HID, meta, noff, nullptr, nullptr, nullptr,
        WvP + (size_t)2 * 16384, bv + (size_t)2 * HID, v,
        WhP, bh, nullptr, nullptr, out_v, N);
}